// Round 20
// baseline (209.379 us; speedup 1.0000x reference)
//
#include <hip/hip_runtime.h>

#define LOSS_OFF 8388608
#define IDX_OFF  8388609

// ws layout (bytes)  (total ~1.58 MB)
#define WS_SEE   0          // float[1024]
#define WS_SXX   4096       // float[32768]   -> 135168
#define WS_KEY   135168     // u64[32768]     -> 397312
#define WS_CNT   397312     // int
#define WS_LOSS  397320     // double
#define WS_WL    397328     // int[32768]     -> 528400
#define WS_EP    528448     // packed E frags (1 MB) during k1; REUSED as eT[c][k] after k1

#define FLT_BIG  3.402823466e+38f
#define MARGIN   1.0e-4f

typedef __attribute__((ext_vector_type(8))) short  short8v;
typedef __attribute__((ext_vector_type(4))) float  float4v;

// async global->LDS, 16B per lane; LDS dest = wave-uniform base (+ lane*16 by HW)
#define GLD16(gp, lp) __builtin_amdgcn_global_load_lds( \
    (const __attribute__((address_space(1))) unsigned int*)(gp), \
    (__attribute__((address_space(3))) unsigned int*)(lp), 16, 0, 0)

// numpy pairwise_sum of 256 squared elements, bit-exact (round-2 notes).
__device__ __forceinline__ float np_sumsq256(const float* __restrict__ p, int stride) {
    float s[2];
#pragma unroll
    for (int half = 0; half < 2; half++) {
        const float* a = p + half * 128 * stride;
        float r[8];
#pragma unroll
        for (int l = 0; l < 8; l++) {
            float v = a[l * stride];
            float sq = v * v;
            asm volatile("" : "+v"(sq));   // forbid fma contraction
            r[l] = sq;
        }
#pragma unroll
        for (int i = 8; i < 128; i += 8) {
#pragma unroll
            for (int l = 0; l < 8; l++) {
                float v = a[(i + l) * stride];
                float sq = v * v;
                asm volatile("" : "+v"(sq));
                r[l] = r[l] + sq;
            }
        }
        s[half] = ((r[0] + r[1]) + (r[2] + r[3])) + ((r[4] + r[5]) + (r[6] + r[7]));
    }
    return s[0] + s[1];
}

__device__ __forceinline__ unsigned int f32_sortable(float m) {
    unsigned int u = __float_as_uint(m);
    return u ^ (((unsigned int)((int)u >> 31)) | 0x80000000u);
}
__device__ __forceinline__ float f32_unsortable(unsigned int s) {   // inverse
    const unsigned int u = (s >> 31) ? (s ^ 0x80000000u) : ~s;
    return __uint_as_float(u);
}

__device__ __forceinline__ unsigned short f2bf(float f) {      // RNE float->bf16
    unsigned int u = __float_as_uint(f);
    return (unsigned short)((u + 0x7fffu + ((u >> 16) & 1u)) >> 16);
}
__device__ __forceinline__ float bf2f(unsigned short h) {
    return __uint_as_float(((unsigned int)h) << 16);
}

// ---------------- k_prep: epack (blocks 0..255) + see/init (blocks 256..259) ----------------
__global__ __launch_bounds__(256) void k_prep(const float* __restrict__ emb,
                                              unsigned short* __restrict__ ebP,
                                              float* __restrict__ see,
                                              int* __restrict__ cnt,
                                              double* __restrict__ loss) {
    const int t = threadIdx.x, bb = blockIdx.x;
    if (bb < 256) {
        const int idx = bb * 256 + t;
        const int l  = idx & 63;
        const int ph = (idx >> 6) & 1;
        const int ct = (idx >> 7) & 7;
        const int cc = (idx >> 10) & 7;
        const int cg = (idx >> 13) & 7;
        const int row = cg * 128 + ct * 16 + (l & 15);
        const int col = cc * 32 + (l >> 4) * 8;
        const float* src = emb + (size_t)row * 256 + col;
        uint4 out;
        unsigned short* op = (unsigned short*)&out;
#pragma unroll
        for (int i = 0; i < 8; i++) {
            const float v = src[i];
            const unsigned short h = f2bf(v);
            op[i] = ph ? f2bf(v - bf2f(h)) : h;      // v-h exact (Sterbenz)
        }
        *(uint4*)(ebP + (size_t)idx * 8) = out;
    } else {
        const int k = (bb - 256) * 256 + t;
        see[k] = np_sumsq256(emb + (size_t)k * 256, 1);
        if (k == 0) { *cnt = 0; *loss = 0.0; }
    }
}

// ---------------- k_et: transpose codebook -> eT[c][k] (runs AFTER k1) ----------------
__global__ __launch_bounds__(256) void k_et(const float* __restrict__ emb,
                                            float* __restrict__ eT) {
    __shared__ float T[256][17];
    const int t  = threadIdx.x;
    const int k0 = blockIdx.x << 4;                 // grid 64
    const int kr = t >> 4, cs = (t & 15) << 4;
#pragma unroll
    for (int j = 0; j < 4; j++) {
        const float4 v = *(const float4*)(emb + (size_t)(k0 + kr) * 256 + cs + j * 4);
        T[cs + j * 4 + 0][kr] = v.x;
        T[cs + j * 4 + 1][kr] = v.y;
        T[cs + j * 4 + 2][kr] = v.z;
        T[cs + j * 4 + 3][kr] = v.w;
    }
    __syncthreads();
    float* dst = eT + (size_t)t * 1024 + k0;
#pragma unroll
    for (int j = 0; j < 4; j++) {
        float4 v;
        v.x = T[t][j * 4 + 0]; v.y = T[t][j * 4 + 1];
        v.z = T[t][j * 4 + 2]; v.w = T[t][j * 4 + 3];
        *(float4*)(dst + j * 4) = v;
    }
}

// ---------------- k1: fused stage+split+sxx+MFMA screen+loss (32-row blocks) ----------------
// grid 1024 x 512 thr. Round-19 lesson: acc[4][8]=128 AGPR + 128 VGPR = 256
// regs/wave pins 8 waves/CU (the m69 register bucket), so fused phases serialize
// and B-load latency is exposed. This round: 32 rows/block, wave = 32r x 128c,
// acc[2][8] = 64 AGPR; __launch_bounds__(512,4) -> 128-reg budget -> VGPR<=64 ->
// 16 waves/CU (2 blocks co-resident: phases overlap the other block's MFMA).
// LDS 64 KB: stage 32K (aliased by reduce arrays post-loop) + frags 32K.
// B L2 traffic doubles (~1 GB ~ 29 us at L2 BW) but overlaps the 25 us MFMA floor.
// All fragment math / fold / margin / worklist bit-identical to rounds 14-19.
__global__ __launch_bounds__(512, 4) void k1_mfma(
        const float* __restrict__ x,
        const unsigned short* __restrict__ ebP,
        const float* __restrict__ see_g,
        float* __restrict__ sxx_g,
        unsigned long long* __restrict__ key,
        double* __restrict__ loss,
        int* __restrict__ cnt, int* __restrict__ wl) {
    __shared__ char smem[65536];
    // [0,32K): x f32 stage [c(256)][row(32)] -- dead after phases B/C; aliased by reduce
    // [32K,64K): bf16 fragments [cc(8)][at(2)][ph(2)][l(64)][16B]
    unsigned long long* lk1 = (unsigned long long*)smem;          // [32][8] 2 KB
    float*              lg2 = (float*)(smem + 2048);              // [32][8] 1 KB
    float* xstage = (float*)smem;
    char*  frag   = smem + 32768;

    const int t = threadIdx.x;
    const int w = t >> 6, l = t & 63;
    const int codeg = w;
    const int lrow = l >> 4, lcol = l & 15;
    const int rb = blockIdx.x;                      // grid 1024
    const int n0 = rb * 32;
    const int b  = rb >> 5;
    const int hw0 = (rb & 31) << 5;

    // Phase A: stage x -> LDS [c][row] f32 (32 KB, 4 GLD16/thread, fully linear)
    {
        const char* xbyte = (const char*)x + ((size_t)b * 262144 + hw0) * 4;
        char* aDst = smem + w * 1024;               // wave-uniform; HW adds lane*16
#pragma unroll
        for (int i = 0; i < 4; i++) {
            const int c = i * 64 + w * 8 + (l >> 3);
            const char* src = xbyte + (size_t)c * 4096 + (size_t)(l & 7) * 16;
            GLD16(src, aDst + i * 8192);
        }
    }
    __syncthreads();

    // Phase C: cooperative bf16 hi/lo split -> packed fragments (2 chunk-pairs/thread)
#pragma unroll
    for (int ii = 0; ii < 2; ii++) {
        const int pi  = ii * 512 + t;          // 0..1023 = [cc(8)][at(2)][l(64)]
        const int pcc = pi >> 7;
        const int pat = (pi >> 6) & 1;
        const int pl  = pi & 63;
        const int prow = pat * 16 + (pl & 15);
        const int pc0  = pcc * 32 + (pl >> 4) * 8;
        uint4 hp, lp;
        unsigned short* hpp = (unsigned short*)&hp;
        unsigned short* lpp = (unsigned short*)&lp;
#pragma unroll
        for (int i = 0; i < 8; i++) {
            const float v = xstage[(pc0 + i) * 32 + prow];
            const unsigned short h = f2bf(v);
            hpp[i] = h;
            lpp[i] = f2bf(v - bf2f(h));        // exact (Sterbenz)
        }
        char* dst = frag + pcc * 4096 + pat * 2048 + pl * 16;
        *(uint4*)dst = hp;
        *(uint4*)(dst + 1024) = lp;
    }
    // Phase B: per-row ||x||^2, np-exact (one row per lane, t<32)
    float sx_reg = 0.f;
    if (t < 32) {
        sx_reg = np_sumsq256(xstage + t, 32);
        sxx_g[n0 + t] = sx_reg;
    }
    __syncthreads();                            // frags+sxx ready; xstage dead

    float4v acc[2][8];
#pragma unroll
    for (int at = 0; at < 2; at++)
#pragma unroll
        for (int ct = 0; ct < 8; ct++) acc[at][ct] = (float4v){0.f, 0.f, 0.f, 0.f};

    for (int cc = 0; cc < 8; cc++) {
        short8v ah[2], al[2];
#pragma unroll
        for (int at = 0; at < 2; at++) {
            const int off = cc * 4096 + at * 2048 + l * 16;
            ah[at] = *(const short8v*)(frag + off);
            al[at] = *(const short8v*)(frag + off + 1024);
        }
#pragma unroll
        for (int ct = 0; ct < 8; ct++) {
            const size_t bb = ((((size_t)codeg * 8 + cc) * 8 + ct) * 2) * 512 + (size_t)l * 8;
            const short8v bh = *(const short8v*)(ebP + bb);
            const short8v bl = *(const short8v*)(ebP + bb + 512);
            __builtin_amdgcn_s_setprio(1);
#pragma unroll
            for (int at = 0; at < 2; at++) {
                acc[at][ct] = __builtin_amdgcn_mfma_f32_16x16x32_bf16(ah[at], bh, acc[at][ct], 0, 0, 0);
                acc[at][ct] = __builtin_amdgcn_mfma_f32_16x16x32_bf16(ah[at], bl, acc[at][ct], 0, 0, 0);
                acc[at][ct] = __builtin_amdgcn_mfma_f32_16x16x32_bf16(al[at], bh, acc[at][ct], 0, 0, 0);
            }
            __builtin_amdgcn_s_setprio(0);
        }
    }

    float sv[8];
#pragma unroll
    for (int ct = 0; ct < 8; ct++) sv[ct] = see_g[codeg * 128 + ct * 16 + lcol];

    // per-row top-2 of g = see - 2*dot_est  (sxx row-constant: order-neutral)
#pragma unroll
    for (int at = 0; at < 2; at++) {
#pragma unroll
        for (int j = 0; j < 4; j++) {
            unsigned long long K1 = ~0ull; float G1 = FLT_BIG, G2 = FLT_BIG;
#pragma unroll
            for (int ct = 0; ct < 8; ct++) {
                const float g = fmaf(-2.f, acc[at][ct][j], sv[ct]);
                const int k = codeg * 128 + ct * 16 + lcol;
                const unsigned long long pk =
                    ((unsigned long long)f32_sortable(g) << 32) | (unsigned int)k;
                if (pk < K1) { G2 = G1; K1 = pk; G1 = g; }
                else         { G2 = fminf(G2, g); }
            }
#pragma unroll
            for (int m = 1; m < 16; m <<= 1) {
                const unsigned long long oK = __shfl_xor(K1, m, 64);
                const float oG2 = __shfl_xor(G2, m, 64);
                const float oG1 = f32_unsortable((unsigned int)(oK >> 32));
                if (oK < K1) { G2 = fminf(oG2, G1); K1 = oK; G1 = oG1; }
                else         { G2 = fminf(G2, oG1); }
            }
            const int rloc = at * 16 + lrow * 4 + j;     // row within 32-row block
            if (lcol == 0) { lk1[rloc * 8 + codeg] = K1; lg2[rloc * 8 + codeg] = G2; }
        }
    }
    __syncthreads();
    if (t < 32) {
        unsigned long long K1 = ~0ull; float G1 = FLT_BIG, G2 = FLT_BIG;
        for (int cg = 0; cg < 8; cg++) {
            const unsigned long long oK = lk1[t * 8 + cg];
            const float oG2 = lg2[t * 8 + cg];
            const float oG1 = f32_unsortable((unsigned int)(oK >> 32));
            if (oK < K1) { G2 = fminf(oG2, G1); K1 = oK; G1 = oG1; }
            else         { G2 = fminf(G2, oG1); }
        }
        const int n = n0 + t;
        if (G2 - G1 > MARGIN) { key[n] = K1; }
        else { key[n] = ~0ull; wl[atomicAdd(cnt, 1)] = n; }
        // loss partial: sum over this block's 32 rows of (sxx + min-dist est)
        float part = sx_reg + G1;
#pragma unroll
        for (int m = 1; m < 32; m <<= 1) part += __shfl_xor(part, m, 64);
        if (t == 0) atomicAdd(loss, (double)part);
    }
}

// ---------------- k2r: np-exact fp32-chain rescan (coalesced via eT) ----------------
__global__ __launch_bounds__(256) void k2r(const float* __restrict__ x,
                                           const float* __restrict__ eT,
                                           const float* __restrict__ see,
                                           const float* __restrict__ sxx,
                                           unsigned long long* __restrict__ key,
                                           const int* __restrict__ cnt,
                                           const int* __restrict__ wl) {
    __shared__ float xs[8][264];
    const int t = threadIdx.x;
    const int total = *cnt;
    for (int base = blockIdx.x * 8; base < total; base += 128 * 8) {
        int nrow[8]; float sx8[8];
#pragma unroll
        for (int r = 0; r < 8; r++) {
            int idx = base + r; if (idx >= total) idx = total - 1;   // benign dup
            const int n = wl[idx];
            nrow[r] = n; sx8[r] = sxx[n];
        }
        __syncthreads();                 // prior batch's xs reads done
#pragma unroll
        for (int r = 0; r < 8; r++) {
            const int n = nrow[r];
            xs[r][t] = x[(size_t)(n >> 10) * 262144 + (size_t)t * 1024 + (n & 1023)];
        }
        __syncthreads();
        float d[8][4];
#pragma unroll
        for (int r = 0; r < 8; r++)
#pragma unroll
            for (int j = 0; j < 4; j++) d[r][j] = 0.f;
#pragma unroll 4
        for (int c = 0; c < 256; c++) {
            float ev[4];
#pragma unroll
            for (int j = 0; j < 4; j++) ev[j] = eT[(size_t)c * 1024 + t + 256 * j];
#pragma unroll
            for (int r = 0; r < 8; r++) {
                const float xv = xs[r][c];
                d[r][0] = fmaf(xv, ev[0], d[r][0]);
                d[r][1] = fmaf(xv, ev[1], d[r][1]);
                d[r][2] = fmaf(xv, ev[2], d[r][2]);
                d[r][3] = fmaf(xv, ev[3], d[r][3]);
            }
        }
#pragma unroll
        for (int r = 0; r < 8; r++) {
            unsigned long long best = ~0ull;
#pragma unroll
            for (int j = 0; j < 4; j++) {
                const float q = fmaf(-2.f, d[r][j], sx8[r]) + see[t + 256 * j];
                const unsigned long long pk =
                    ((unsigned long long)f32_sortable(q) << 32) | (unsigned int)(t + 256 * j);
                best = pk < best ? pk : best;
            }
            atomicMin(&key[nrow[r]], best);
        }
    }
}

// ---------------- k3: gather quantized + indices ----------------
__global__ __launch_bounds__(256) void k3_out(const float* __restrict__ emb,
                                              const unsigned long long* __restrict__ key,
                                              float* __restrict__ dout) {
    __shared__ float elds[32][257];
    __shared__ int   idxs[32];
    const int t  = threadIdx.x;
    const int bh = blockIdx.x;
    const int b = bh >> 5, h = bh & 31;
    if (t < 32) idxs[t] = (int)(key[(bh << 5) + t] & 0xffffffffull);
    __syncthreads();
    for (int r = 0; r < 32; r++) elds[r][t] = emb[(size_t)idxs[r] * 256 + t];
    __syncthreads();
    const int w = t & 31, cg = t >> 5;
    const size_t base = (size_t)b * 262144 + (size_t)(h * 32 + w);
#pragma unroll 4
    for (int s = 0; s < 32; s++) {
        const int c = (cg << 5) + s;
        dout[base + (size_t)c * 1024] = elds[w][c];
    }
    if (t < 32) dout[IDX_OFF + (bh << 5) + t] = (float)idxs[t];
}

// ---------------- k4: finalize loss ----------------
__global__ void k4_fin(const double* __restrict__ loss, float* __restrict__ dout) {
    dout[LOSS_OFF] = (float)(1.25 * (*loss) / 8388608.0);
}

extern "C" void kernel_launch(void* const* d_in, const int* in_sizes, int n_in,
                              void* d_out, int out_size, void* d_ws, size_t ws_size,
                              hipStream_t stream) {
    const float* x   = (const float*)d_in[0];
    const float* emb = (const float*)d_in[1];
    float* dout = (float*)d_out;
    char* ws = (char*)d_ws;
    float*  see  = (float*)(ws + WS_SEE);
    float*  sxx  = (float*)(ws + WS_SXX);
    unsigned long long* key = (unsigned long long*)(ws + WS_KEY);
    int*    cnt  = (int*)(ws + WS_CNT);
    double* loss = (double*)(ws + WS_LOSS);
    int*    wl   = (int*)(ws + WS_WL);
    unsigned short* ebP = (unsigned short*)(ws + WS_EP);
    float*  eT   = (float*)(ws + WS_EP);      // same region: ebP dead after k1

    k_prep <<<260,  256, 0, stream>>>(emb, ebP, see, cnt, loss);
    k1_mfma<<<1024, 512, 0, stream>>>(x, ebP, see, sxx, key, loss, cnt, wl);
    k_et   <<<64,   256, 0, stream>>>(emb, eT);          // overwrites ebP region
    k2r    <<<128,  256, 0, stream>>>(x, eT, see, sxx, key, cnt, wl);
    k3_out <<<1024, 256, 0, stream>>>(emb, key, dout);
    k4_fin <<<1,      1, 0, stream>>>(loss, dout);
}

// Round 21
// 180.284 us; speedup vs baseline: 1.1614x; 1.1614x over previous
//
#include <hip/hip_runtime.h>

#define LOSS_OFF 8388608
#define IDX_OFF  8388609

// ws layout (bytes)  (total ~1.58 MB)
#define WS_SEE   0          // float[1024]
#define WS_SXX   4096       // float[32768]   -> 135168
#define WS_KEY   135168     // u64[32768]     -> 397312
#define WS_CNT   397312     // int
#define WS_LOSS  397320     // double
#define WS_WL    397328     // int[32768]     -> 528400
#define WS_EP    528448     // packed E frags (1 MB)

#define FLT_BIG  3.402823466e+38f
#define MARGIN   1.0e-4f

typedef __attribute__((ext_vector_type(8))) short  short8v;
typedef __attribute__((ext_vector_type(4))) float  float4v;

// async global->LDS, 16B per lane; LDS dest = wave-uniform base (+ lane*16 by HW)
#define GLD16(gp, lp) __builtin_amdgcn_global_load_lds( \
    (const __attribute__((address_space(1))) unsigned int*)(gp), \
    (__attribute__((address_space(3))) unsigned int*)(lp), 16, 0, 0)

// numpy pairwise_sum of 256 squared elements, bit-exact (round-2 notes).
__device__ __forceinline__ float np_sumsq256(const float* __restrict__ p, int stride) {
    float s[2];
#pragma unroll
    for (int half = 0; half < 2; half++) {
        const float* a = p + half * 128 * stride;
        float r[8];
#pragma unroll
        for (int l = 0; l < 8; l++) {
            float v = a[l * stride];
            float sq = v * v;
            asm volatile("" : "+v"(sq));   // forbid fma contraction
            r[l] = sq;
        }
#pragma unroll
        for (int i = 8; i < 128; i += 8) {
#pragma unroll
            for (int l = 0; l < 8; l++) {
                float v = a[(i + l) * stride];
                float sq = v * v;
                asm volatile("" : "+v"(sq));
                r[l] = r[l] + sq;
            }
        }
        s[half] = ((r[0] + r[1]) + (r[2] + r[3])) + ((r[4] + r[5]) + (r[6] + r[7]));
    }
    return s[0] + s[1];
}

__device__ __forceinline__ unsigned int f32_sortable(float m) {
    unsigned int u = __float_as_uint(m);
    return u ^ (((unsigned int)((int)u >> 31)) | 0x80000000u);
}
__device__ __forceinline__ float f32_unsortable(unsigned int s) {   // inverse
    const unsigned int u = (s >> 31) ? (s ^ 0x80000000u) : ~s;
    return __uint_as_float(u);
}

__device__ __forceinline__ unsigned short f2bf(float f) {      // RNE float->bf16
    unsigned int u = __float_as_uint(f);
    return (unsigned short)((u + 0x7fffu + ((u >> 16) & 1u)) >> 16);
}
__device__ __forceinline__ float bf2f(unsigned short h) {
    return __uint_as_float(((unsigned int)h) << 16);
}

// ---------------- k_prep: epack (0..255) + see/init (256..259) + eT (260..323) ----------------
// eT[c][k] (exact f32 transpose for k2r) goes into d_out's quantized region --
// dead until k3 overwrites it; k2r reads it in between. Saves the k_et launch.
__global__ __launch_bounds__(256) void k_prep(const float* __restrict__ emb,
                                              unsigned short* __restrict__ ebP,
                                              float* __restrict__ see,
                                              float* __restrict__ eT,
                                              int* __restrict__ cnt,
                                              double* __restrict__ loss) {
    const int t = threadIdx.x, bb = blockIdx.x;
    if (bb < 256) {
        const int idx = bb * 256 + t;
        const int l  = idx & 63;
        const int ph = (idx >> 6) & 1;
        const int ct = (idx >> 7) & 7;
        const int cc = (idx >> 10) & 7;
        const int cg = (idx >> 13) & 7;
        const int row = cg * 128 + ct * 16 + (l & 15);
        const int col = cc * 32 + (l >> 4) * 8;
        const float* src = emb + (size_t)row * 256 + col;
        uint4 out;
        unsigned short* op = (unsigned short*)&out;
#pragma unroll
        for (int i = 0; i < 8; i++) {
            const float v = src[i];
            const unsigned short h = f2bf(v);
            op[i] = ph ? f2bf(v - bf2f(h)) : h;      // v-h exact (Sterbenz)
        }
        *(uint4*)(ebP + (size_t)idx * 8) = out;
    } else if (bb < 260) {
        const int k = (bb - 256) * 256 + t;
        see[k] = np_sumsq256(emb + (size_t)k * 256, 1);
        if (k == 0) { *cnt = 0; *loss = 0.0; }
    } else {
        // transpose 16 codes -> eT[c][k]
        __shared__ float T[256][17];
        const int k0 = (bb - 260) << 4;
        const int kr = t >> 4, cs = (t & 15) << 4;
#pragma unroll
        for (int j = 0; j < 4; j++) {
            const float4 v = *(const float4*)(emb + (size_t)(k0 + kr) * 256 + cs + j * 4);
            T[cs + j * 4 + 0][kr] = v.x;
            T[cs + j * 4 + 1][kr] = v.y;
            T[cs + j * 4 + 2][kr] = v.z;
            T[cs + j * 4 + 3][kr] = v.w;
        }
        __syncthreads();
        float* dst = eT + (size_t)t * 1024 + k0;
#pragma unroll
        for (int j = 0; j < 4; j++) {
            float4 v;
            v.x = T[t][j * 4 + 0]; v.y = T[t][j * 4 + 1];
            v.z = T[t][j * 4 + 2]; v.w = T[t][j * 4 + 3];
            *(float4*)(dst + j * 4) = v;
        }
    }
}

// ---------------- k1: fused stage+split+sxx+MFMA screen+loss (round-19 geometry) ----------------
// grid 512 x 512 thr (8 waves, launch_bounds(512,2); LDS 128 KB -> 1 block/CU).
// NO setprio this round: m190 measured setprio HURTS barrier-synced lockstep
// GEMM waves (it rode along since round 18: k1 68->73 us that round).
// Phases + main loop + fold byte-identical to round 19 otherwise.
__global__ __launch_bounds__(512, 2) void k1_mfma(
        const float* __restrict__ x,
        const unsigned short* __restrict__ ebP,
        const float* __restrict__ see_g,
        float* __restrict__ sxx_g,
        unsigned long long* __restrict__ key,
        double* __restrict__ loss,
        int* __restrict__ cnt, int* __restrict__ wl) {
    __shared__ char smem[131072];
    unsigned long long* lk1 = (unsigned long long*)smem;          // [64][8] 4 KB (aliases xstage)
    float*              lg2 = (float*)(smem + 4096);              // [64][8] 2 KB
    float* xstage = (float*)smem;
    char*  frag   = smem + 65536;

    const int t = threadIdx.x;
    const int w = t >> 6, l = t & 63;
    const int codeg = w;
    const int lrow = l >> 4, lcol = l & 15;
    const int rb = blockIdx.x;
    const int n0 = rb * 64;
    const int b  = rb >> 4;
    const int hw0 = (rb & 15) << 6;

    // Phase A: stage x -> LDS [c][row] f32 (64 KB, linear GLD16)
    {
        const char* xbyte = (const char*)x + ((size_t)b * 262144 + hw0) * 4;
#pragma unroll
        for (int i = 0; i < 8; i++) {
            const int cbase = i * 32 + w * 4;
            const char* src = xbyte + (size_t)(cbase + (l >> 4)) * 4096 + (size_t)(l & 15) * 16;
            GLD16(src, smem + cbase * 256);
        }
    }
    __syncthreads();

    // Phase C: cooperative bf16 hi/lo split -> packed fragments
#pragma unroll
    for (int ii = 0; ii < 4; ii++) {
        const int pi  = ii * 512 + t;          // 0..2047 = [cc(8)][at(4)][l(64)]
        const int pcc = pi >> 8;
        const int pat = (pi >> 6) & 3;
        const int pl  = pi & 63;
        const int prow = pat * 16 + (pl & 15);
        const int pc0  = pcc * 32 + (pl >> 4) * 8;
        uint4 hp, lp;
        unsigned short* hpp = (unsigned short*)&hp;
        unsigned short* lpp = (unsigned short*)&lp;
#pragma unroll
        for (int i = 0; i < 8; i++) {
            const float v = xstage[(pc0 + i) * 64 + prow];
            const unsigned short h = f2bf(v);
            hpp[i] = h;
            lpp[i] = f2bf(v - bf2f(h));        // exact (Sterbenz)
        }
        char* dst = frag + pcc * 8192 + pat * 2048 + pl * 16;
        *(uint4*)dst = hp;
        *(uint4*)(dst + 1024) = lp;
    }
    // Phase B: per-row ||x||^2, np-exact (wave 0; one row per lane; 2-way banks = free)
    float sx_reg = 0.f;
    if (t < 64) {
        sx_reg = np_sumsq256(xstage + t, 64);
        sxx_g[n0 + t] = sx_reg;
    }
    __syncthreads();                            // frags+sxx ready; xstage dead

    float4v acc[4][8];
#pragma unroll
    for (int at = 0; at < 4; at++)
#pragma unroll
        for (int ct = 0; ct < 8; ct++) acc[at][ct] = (float4v){0.f, 0.f, 0.f, 0.f};

    for (int cc = 0; cc < 8; cc++) {
        short8v ah[4], al[4];
#pragma unroll
        for (int at = 0; at < 4; at++) {
            const int off = cc * 8192 + at * 2048 + l * 16;
            ah[at] = *(const short8v*)(frag + off);
            al[at] = *(const short8v*)(frag + off + 1024);
        }
#pragma unroll
        for (int ct = 0; ct < 8; ct++) {
            const size_t bb = ((((size_t)codeg * 8 + cc) * 8 + ct) * 2) * 512 + (size_t)l * 8;
            const short8v bh = *(const short8v*)(ebP + bb);
            const short8v bl = *(const short8v*)(ebP + bb + 512);
#pragma unroll
            for (int at = 0; at < 4; at++) {
                acc[at][ct] = __builtin_amdgcn_mfma_f32_16x16x32_bf16(ah[at], bh, acc[at][ct], 0, 0, 0);
                acc[at][ct] = __builtin_amdgcn_mfma_f32_16x16x32_bf16(ah[at], bl, acc[at][ct], 0, 0, 0);
                acc[at][ct] = __builtin_amdgcn_mfma_f32_16x16x32_bf16(al[at], bh, acc[at][ct], 0, 0, 0);
            }
        }
    }

    float sv[8];
#pragma unroll
    for (int ct = 0; ct < 8; ct++) sv[ct] = see_g[codeg * 128 + ct * 16 + lcol];

    // per-row top-2 of g = see - 2*dot_est  (sxx row-constant: order-neutral)
#pragma unroll
    for (int at = 0; at < 4; at++) {
#pragma unroll
        for (int j = 0; j < 4; j++) {
            unsigned long long K1 = ~0ull; float G1 = FLT_BIG, G2 = FLT_BIG;
#pragma unroll
            for (int ct = 0; ct < 8; ct++) {
                const float g = fmaf(-2.f, acc[at][ct][j], sv[ct]);
                const int k = codeg * 128 + ct * 16 + lcol;
                const unsigned long long pk =
                    ((unsigned long long)f32_sortable(g) << 32) | (unsigned int)k;
                if (pk < K1) { G2 = G1; K1 = pk; G1 = g; }
                else         { G2 = fminf(G2, g); }
            }
#pragma unroll
            for (int m = 1; m < 16; m <<= 1) {
                const unsigned long long oK = __shfl_xor(K1, m, 64);
                const float oG2 = __shfl_xor(G2, m, 64);
                const float oG1 = f32_unsortable((unsigned int)(oK >> 32));
                if (oK < K1) { G2 = fminf(oG2, G1); K1 = oK; G1 = oG1; }
                else         { G2 = fminf(G2, oG1); }
            }
            const int rloc = at * 16 + lrow * 4 + j;
            if (lcol == 0) { lk1[rloc * 8 + codeg] = K1; lg2[rloc * 8 + codeg] = G2; }
        }
    }
    __syncthreads();
    if (t < 64) {
        unsigned long long K1 = ~0ull; float G1 = FLT_BIG, G2 = FLT_BIG;
        for (int cg = 0; cg < 8; cg++) {
            const unsigned long long oK = lk1[t * 8 + cg];
            const float oG2 = lg2[t * 8 + cg];
            const float oG1 = f32_unsortable((unsigned int)(oK >> 32));
            if (oK < K1) { G2 = fminf(oG2, G1); K1 = oK; G1 = oG1; }
            else         { G2 = fminf(G2, oG1); }
        }
        const int n = n0 + t;
        if (G2 - G1 > MARGIN) { key[n] = K1; }
        else { key[n] = ~0ull; wl[atomicAdd(cnt, 1)] = n; }
        // loss partial: sum over this block's 64 rows of (sxx + min-dist est)
        float part = sx_reg + G1;
#pragma unroll
        for (int m = 1; m < 64; m <<= 1) part += __shfl_xor(part, m, 64);
        if (t == 0) atomicAdd(loss, (double)part);
    }
}

// ---------------- k2r: np-exact fp32-chain rescan (coalesced via eT in d_out) ----------------
__global__ __launch_bounds__(256) void k2r(const float* __restrict__ x,
                                           const float* __restrict__ eT,
                                           const float* __restrict__ see,
                                           const float* __restrict__ sxx,
                                           unsigned long long* __restrict__ key,
                                           const int* __restrict__ cnt,
                                           const int* __restrict__ wl) {
    __shared__ float xs[8][264];
    const int t = threadIdx.x;
    const int total = *cnt;
    for (int base = blockIdx.x * 8; base < total; base += 128 * 8) {
        int nrow[8]; float sx8[8];
#pragma unroll
        for (int r = 0; r < 8; r++) {
            int idx = base + r; if (idx >= total) idx = total - 1;   // benign dup
            const int n = wl[idx];
            nrow[r] = n; sx8[r] = sxx[n];
        }
        __syncthreads();                 // prior batch's xs reads done
#pragma unroll
        for (int r = 0; r < 8; r++) {
            const int n = nrow[r];
            xs[r][t] = x[(size_t)(n >> 10) * 262144 + (size_t)t * 1024 + (n & 1023)];
        }
        __syncthreads();
        float d[8][4];
#pragma unroll
        for (int r = 0; r < 8; r++)
#pragma unroll
            for (int j = 0; j < 4; j++) d[r][j] = 0.f;
#pragma unroll 4
        for (int c = 0; c < 256; c++) {
            float ev[4];
#pragma unroll
            for (int j = 0; j < 4; j++) ev[j] = eT[(size_t)c * 1024 + t + 256 * j];
#pragma unroll
            for (int r = 0; r < 8; r++) {
                const float xv = xs[r][c];
                d[r][0] = fmaf(xv, ev[0], d[r][0]);
                d[r][1] = fmaf(xv, ev[1], d[r][1]);
                d[r][2] = fmaf(xv, ev[2], d[r][2]);
                d[r][3] = fmaf(xv, ev[3], d[r][3]);
            }
        }
#pragma unroll
        for (int r = 0; r < 8; r++) {
            unsigned long long best = ~0ull;
#pragma unroll
            for (int j = 0; j < 4; j++) {
                const float q = fmaf(-2.f, d[r][j], sx8[r]) + see[t + 256 * j];
                const unsigned long long pk =
                    ((unsigned long long)f32_sortable(q) << 32) | (unsigned int)(t + 256 * j);
                best = pk < best ? pk : best;
            }
            atomicMin(&key[nrow[r]], best);
        }
    }
}

// ---------------- k3: gather quantized + indices + loss finalize ----------------
__global__ __launch_bounds__(256) void k3_out(const float* __restrict__ emb,
                                              const unsigned long long* __restrict__ key,
                                              const double* __restrict__ loss,
                                              float* __restrict__ dout) {
    __shared__ float elds[32][257];
    __shared__ int   idxs[32];
    const int t  = threadIdx.x;
    const int bh = blockIdx.x;
    const int b = bh >> 5, h = bh & 31;
    if (t < 32) idxs[t] = (int)(key[(bh << 5) + t] & 0xffffffffull);
    __syncthreads();
    for (int r = 0; r < 32; r++) elds[r][t] = emb[(size_t)idxs[r] * 256 + t];
    __syncthreads();
    const int w = t & 31, cg = t >> 5;
    const size_t base = (size_t)b * 262144 + (size_t)(h * 32 + w);
#pragma unroll 4
    for (int s = 0; s < 32; s++) {
        const int c = (cg << 5) + s;
        dout[base + (size_t)c * 1024] = elds[w][c];
    }
    if (t < 32) dout[IDX_OFF + (bh << 5) + t] = (float)idxs[t];
    if (bh == 0 && t == 0)
        dout[LOSS_OFF] = (float)(1.25 * (*loss) / 8388608.0);
}

extern "C" void kernel_launch(void* const* d_in, const int* in_sizes, int n_in,
                              void* d_out, int out_size, void* d_ws, size_t ws_size,
                              hipStream_t stream) {
    const float* x   = (const float*)d_in[0];
    const float* emb = (const float*)d_in[1];
    float* dout = (float*)d_out;
    char* ws = (char*)d_ws;
    float*  see  = (float*)(ws + WS_SEE);
    float*  sxx  = (float*)(ws + WS_SXX);
    unsigned long long* key = (unsigned long long*)(ws + WS_KEY);
    int*    cnt  = (int*)(ws + WS_CNT);
    double* loss = (double*)(ws + WS_LOSS);
    int*    wl   = (int*)(ws + WS_WL);
    unsigned short* ebP = (unsigned short*)(ws + WS_EP);
    // eT (exact f32 transpose for k2r) lives in d_out's quantized region:
    // written by k_prep, read by k2r, overwritten by k3. 1 MB << 32 MB region.
    float* eT = dout;

    k_prep <<<324,  256, 0, stream>>>(emb, ebP, see, eT, cnt, loss);
    k1_mfma<<<512,  512, 0, stream>>>(x, ebP, see, sxx, key, loss, cnt, wl);
    k2r    <<<128,  256, 0, stream>>>(x, eT, see, sxx, key, cnt, wl);
    k3_out <<<1024, 256, 0, stream>>>(emb, key, loss, dout);
}

// Round 22
// 178.641 us; speedup vs baseline: 1.1721x; 1.0092x over previous
//
#include <hip/hip_runtime.h>

#define LOSS_OFF 8388608
#define IDX_OFF  8388609

// ws layout (bytes)  (total ~1.58 MB)
#define WS_SEE   0          // float[1024]
#define WS_SXX   4096       // float[32768]   -> 135168
#define WS_KEY   135168     // u64[32768]     -> 397312
#define WS_CNT   397312     // int
#define WS_LOSS  397320     // double
#define WS_WL    397328     // int[32768]     -> 528400
#define WS_EP    528448     // packed E frags (1 MB)

#define FLT_BIG  3.402823466e+38f
#define MARGIN   1.0e-4f

typedef __attribute__((ext_vector_type(8))) short  short8v;
typedef __attribute__((ext_vector_type(4))) float  float4v;

// async global->LDS, 16B per lane; LDS dest = wave-uniform base (+ lane*16 by HW)
#define GLD16(gp, lp) __builtin_amdgcn_global_load_lds( \
    (const __attribute__((address_space(1))) unsigned int*)(gp), \
    (__attribute__((address_space(3))) unsigned int*)(lp), 16, 0, 0)

// numpy pairwise_sum of 256 squared elements, bit-exact (round-2 notes).
__device__ __forceinline__ float np_sumsq256(const float* __restrict__ p, int stride) {
    float s[2];
#pragma unroll
    for (int half = 0; half < 2; half++) {
        const float* a = p + half * 128 * stride;
        float r[8];
#pragma unroll
        for (int l = 0; l < 8; l++) {
            float v = a[l * stride];
            float sq = v * v;
            asm volatile("" : "+v"(sq));   // forbid fma contraction
            r[l] = sq;
        }
#pragma unroll
        for (int i = 8; i < 128; i += 8) {
#pragma unroll
            for (int l = 0; l < 8; l++) {
                float v = a[(i + l) * stride];
                float sq = v * v;
                asm volatile("" : "+v"(sq));
                r[l] = r[l] + sq;
            }
        }
        s[half] = ((r[0] + r[1]) + (r[2] + r[3])) + ((r[4] + r[5]) + (r[6] + r[7]));
    }
    return s[0] + s[1];
}

__device__ __forceinline__ unsigned int f32_sortable(float m) {
    unsigned int u = __float_as_uint(m);
    return u ^ (((unsigned int)((int)u >> 31)) | 0x80000000u);
}
__device__ __forceinline__ float f32_unsortable(unsigned int s) {   // inverse
    const unsigned int u = (s >> 31) ? (s ^ 0x80000000u) : ~s;
    return __uint_as_float(u);
}

__device__ __forceinline__ unsigned short f2bf(float f) {      // RNE float->bf16
    unsigned int u = __float_as_uint(f);
    return (unsigned short)((u + 0x7fffu + ((u >> 16) & 1u)) >> 16);
}
__device__ __forceinline__ float bf2f(unsigned short h) {
    return __uint_as_float(((unsigned int)h) << 16);
}

// ---------------- k_prep: epack (0..255) + see/init (256..259) + eT (260..323) ----------------
__global__ __launch_bounds__(256) void k_prep(const float* __restrict__ emb,
                                              unsigned short* __restrict__ ebP,
                                              float* __restrict__ see,
                                              float* __restrict__ eT,
                                              int* __restrict__ cnt,
                                              double* __restrict__ loss) {
    const int t = threadIdx.x, bb = blockIdx.x;
    if (bb < 256) {
        const int idx = bb * 256 + t;
        const int l  = idx & 63;
        const int ph = (idx >> 6) & 1;
        const int ct = (idx >> 7) & 7;
        const int cc = (idx >> 10) & 7;
        const int cg = (idx >> 13) & 7;
        const int row = cg * 128 + ct * 16 + (l & 15);
        const int col = cc * 32 + (l >> 4) * 8;
        const float* src = emb + (size_t)row * 256 + col;
        uint4 out;
        unsigned short* op = (unsigned short*)&out;
#pragma unroll
        for (int i = 0; i < 8; i++) {
            const float v = src[i];
            const unsigned short h = f2bf(v);
            op[i] = ph ? f2bf(v - bf2f(h)) : h;      // v-h exact (Sterbenz)
        }
        *(uint4*)(ebP + (size_t)idx * 8) = out;
    } else if (bb < 260) {
        const int k = (bb - 256) * 256 + t;
        see[k] = np_sumsq256(emb + (size_t)k * 256, 1);
        if (k == 0) { *cnt = 0; *loss = 0.0; }
    } else {
        // transpose 16 codes -> eT[c][k] (in d_out's quantized region; k2r reads, k3 overwrites)
        __shared__ float T[256][17];
        const int k0 = (bb - 260) << 4;
        const int kr = t >> 4, cs = (t & 15) << 4;
#pragma unroll
        for (int j = 0; j < 4; j++) {
            const float4 v = *(const float4*)(emb + (size_t)(k0 + kr) * 256 + cs + j * 4);
            T[cs + j * 4 + 0][kr] = v.x;
            T[cs + j * 4 + 1][kr] = v.y;
            T[cs + j * 4 + 2][kr] = v.z;
            T[cs + j * 4 + 3][kr] = v.w;
        }
        __syncthreads();
        float* dst = eT + (size_t)t * 1024 + k0;
#pragma unroll
        for (int j = 0; j < 4; j++) {
            float4 v;
            v.x = T[t][j * 4 + 0]; v.y = T[t][j * 4 + 1];
            v.z = T[t][j * 4 + 2]; v.w = T[t][j * 4 + 3];
            *(float4*)(dst + j * 4) = v;
        }
    }
}

// issue 8 B-loads (4 ct, hi+lo) into a register buffer -- static indices only
#define LOADB(buf, ccv, cth) do {                                              \
    _Pragma("unroll")                                                          \
    for (int q = 0; q < 4; q++) {                                              \
        const int ctq = (cth) * 4 + q;                                         \
        const size_t bbq = ((((size_t)codeg * 8 + (ccv)) * 8 + ctq) * 2) * 512 \
                           + (size_t)l * 8;                                    \
        buf[2 * q]     = *(const short8v*)(ebP + bbq);                         \
        buf[2 * q + 1] = *(const short8v*)(ebP + bbq + 512);                   \
    }                                                                          \
} while (0)

// 12 MFMAs for one ct (3-product accumulate) -- order identical to rounds 14-21
#define MFMA_CT(ctv, BH, BL) do {                                              \
    _Pragma("unroll")                                                          \
    for (int at = 0; at < 4; at++) {                                           \
        acc[at][ctv] = __builtin_amdgcn_mfma_f32_16x16x32_bf16(ah[at], BH, acc[at][ctv], 0, 0, 0); \
        acc[at][ctv] = __builtin_amdgcn_mfma_f32_16x16x32_bf16(ah[at], BL, acc[at][ctv], 0, 0, 0); \
        acc[at][ctv] = __builtin_amdgcn_mfma_f32_16x16x32_bf16(al[at], BH, acc[at][ctv], 0, 0, 0); \
    }                                                                          \
} while (0)

// ---------------- k1: fused stage+split+sxx+MFMA screen+loss (B double-buffered) ----------------
// grid 512 x 512 thr (8 waves, launch_bounds(512,2); LDS 128 KB; 1 block/CU --
// acc[4][8]=128 AGPR + 128 VGPR = 256 regs/wave caps 8 waves/CU, so latency
// hiding must come from ILP: B is double-buffered at half-cc granularity
// (two 8x short8v buffers = 64 VGPR); each B batch gets ~240cy of MFMA between
// issue and first use (round 21: loads issued at point of use -> ~40us stall).
// MFMA order (cc asc, ct asc, (ah,bh)(ah,bl)(al,bh)) bit-identical.
__global__ __launch_bounds__(512, 2) void k1_mfma(
        const float* __restrict__ x,
        const unsigned short* __restrict__ ebP,
        const float* __restrict__ see_g,
        float* __restrict__ sxx_g,
        unsigned long long* __restrict__ key,
        double* __restrict__ loss,
        int* __restrict__ cnt, int* __restrict__ wl) {
    __shared__ char smem[131072];
    unsigned long long* lk1 = (unsigned long long*)smem;          // [64][8] 4 KB (aliases xstage)
    float*              lg2 = (float*)(smem + 4096);              // [64][8] 2 KB
    float* xstage = (float*)smem;
    char*  frag   = smem + 65536;

    const int t = threadIdx.x;
    const int w = t >> 6, l = t & 63;
    const int codeg = w;
    const int lrow = l >> 4, lcol = l & 15;
    const int rb = blockIdx.x;
    const int n0 = rb * 64;
    const int b  = rb >> 4;
    const int hw0 = (rb & 15) << 6;

    // Phase A: stage x -> LDS [c][row] f32 (64 KB, linear GLD16)
    {
        const char* xbyte = (const char*)x + ((size_t)b * 262144 + hw0) * 4;
#pragma unroll
        for (int i = 0; i < 8; i++) {
            const int cbase = i * 32 + w * 4;
            const char* src = xbyte + (size_t)(cbase + (l >> 4)) * 4096 + (size_t)(l & 15) * 16;
            GLD16(src, smem + cbase * 256);
        }
    }
    __syncthreads();

    // Phase C: cooperative bf16 hi/lo split -> packed fragments
#pragma unroll
    for (int ii = 0; ii < 4; ii++) {
        const int pi  = ii * 512 + t;          // 0..2047 = [cc(8)][at(4)][l(64)]
        const int pcc = pi >> 8;
        const int pat = (pi >> 6) & 3;
        const int pl  = pi & 63;
        const int prow = pat * 16 + (pl & 15);
        const int pc0  = pcc * 32 + (pl >> 4) * 8;
        uint4 hp, lp;
        unsigned short* hpp = (unsigned short*)&hp;
        unsigned short* lpp = (unsigned short*)&lp;
#pragma unroll
        for (int i = 0; i < 8; i++) {
            const float v = xstage[(pc0 + i) * 64 + prow];
            const unsigned short h = f2bf(v);
            hpp[i] = h;
            lpp[i] = f2bf(v - bf2f(h));        // exact (Sterbenz)
        }
        char* dst = frag + pcc * 8192 + pat * 2048 + pl * 16;
        *(uint4*)dst = hp;
        *(uint4*)(dst + 1024) = lp;
    }
    // Phase B: per-row ||x||^2, np-exact (wave 0; one row per lane)
    float sx_reg = 0.f;
    if (t < 64) {
        sx_reg = np_sumsq256(xstage + t, 64);
        sxx_g[n0 + t] = sx_reg;
    }
    __syncthreads();                            // frags+sxx ready; xstage dead

    float4v acc[4][8];
#pragma unroll
    for (int at = 0; at < 4; at++)
#pragma unroll
        for (int ct = 0; ct < 8; ct++) acc[at][ct] = (float4v){0.f, 0.f, 0.f, 0.f};

    short8v b0[8], b1[8];
    LOADB(b0, 0, 0);                            // prime: (cc=0, half 0)
    for (int cc = 0; cc < 8; cc++) {
        short8v ah[4], al[4];
#pragma unroll
        for (int at = 0; at < 4; at++) {
            const int off = cc * 8192 + at * 2048 + l * 16;
            ah[at] = *(const short8v*)(frag + off);
            al[at] = *(const short8v*)(frag + off + 1024);
        }
        LOADB(b1, cc, 1);                       // issue half 1 before computing half 0
        MFMA_CT(0, b0[0], b0[1]);
        MFMA_CT(1, b0[2], b0[3]);
        MFMA_CT(2, b0[4], b0[5]);
        MFMA_CT(3, b0[6], b0[7]);
        if (cc < 7) LOADB(b0, cc + 1, 0);       // issue next cc's half 0 under half 1's MFMAs
        MFMA_CT(4, b1[0], b1[1]);
        MFMA_CT(5, b1[2], b1[3]);
        MFMA_CT(6, b1[4], b1[5]);
        MFMA_CT(7, b1[6], b1[7]);
    }

    float sv[8];
#pragma unroll
    for (int ct = 0; ct < 8; ct++) sv[ct] = see_g[codeg * 128 + ct * 16 + lcol];

    // per-row top-2 of g = see - 2*dot_est  (sxx row-constant: order-neutral)
#pragma unroll
    for (int at = 0; at < 4; at++) {
#pragma unroll
        for (int j = 0; j < 4; j++) {
            unsigned long long K1 = ~0ull; float G1 = FLT_BIG, G2 = FLT_BIG;
#pragma unroll
            for (int ct = 0; ct < 8; ct++) {
                const float g = fmaf(-2.f, acc[at][ct][j], sv[ct]);
                const int k = codeg * 128 + ct * 16 + lcol;
                const unsigned long long pk =
                    ((unsigned long long)f32_sortable(g) << 32) | (unsigned int)k;
                if (pk < K1) { G2 = G1; K1 = pk; G1 = g; }
                else         { G2 = fminf(G2, g); }
            }
#pragma unroll
            for (int m = 1; m < 16; m <<= 1) {
                const unsigned long long oK = __shfl_xor(K1, m, 64);
                const float oG2 = __shfl_xor(G2, m, 64);
                const float oG1 = f32_unsortable((unsigned int)(oK >> 32));
                if (oK < K1) { G2 = fminf(oG2, G1); K1 = oK; G1 = oG1; }
                else         { G2 = fminf(G2, oG1); }
            }
            const int rloc = at * 16 + lrow * 4 + j;
            if (lcol == 0) { lk1[rloc * 8 + codeg] = K1; lg2[rloc * 8 + codeg] = G2; }
        }
    }
    __syncthreads();
    if (t < 64) {
        unsigned long long K1 = ~0ull; float G1 = FLT_BIG, G2 = FLT_BIG;
        for (int cg = 0; cg < 8; cg++) {
            const unsigned long long oK = lk1[t * 8 + cg];
            const float oG2 = lg2[t * 8 + cg];
            const float oG1 = f32_unsortable((unsigned int)(oK >> 32));
            if (oK < K1) { G2 = fminf(oG2, G1); K1 = oK; G1 = oG1; }
            else         { G2 = fminf(G2, oG1); }
        }
        const int n = n0 + t;
        if (G2 - G1 > MARGIN) { key[n] = K1; }
        else { key[n] = ~0ull; wl[atomicAdd(cnt, 1)] = n; }
        // loss partial: sum over this block's 64 rows of (sxx + min-dist est)
        float part = sx_reg + G1;
#pragma unroll
        for (int m = 1; m < 64; m <<= 1) part += __shfl_xor(part, m, 64);
        if (t == 0) atomicAdd(loss, (double)part);
    }
}

// ---------------- k2r: np-exact fp32-chain rescan (coalesced via eT in d_out) ----------------
__global__ __launch_bounds__(256) void k2r(const float* __restrict__ x,
                                           const float* __restrict__ eT,
                                           const float* __restrict__ see,
                                           const float* __restrict__ sxx,
                                           unsigned long long* __restrict__ key,
                                           const int* __restrict__ cnt,
                                           const int* __restrict__ wl) {
    __shared__ float xs[8][264];
    const int t = threadIdx.x;
    const int total = *cnt;
    for (int base = blockIdx.x * 8; base < total; base += 128 * 8) {
        int nrow[8]; float sx8[8];
#pragma unroll
        for (int r = 0; r < 8; r++) {
            int idx = base + r; if (idx >= total) idx = total - 1;   // benign dup
            const int n = wl[idx];
            nrow[r] = n; sx8[r] = sxx[n];
        }
        __syncthreads();                 // prior batch's xs reads done
#pragma unroll
        for (int r = 0; r < 8; r++) {
            const int n = nrow[r];
            xs[r][t] = x[(size_t)(n >> 10) * 262144 + (size_t)t * 1024 + (n & 1023)];
        }
        __syncthreads();
        float d[8][4];
#pragma unroll
        for (int r = 0; r < 8; r++)
#pragma unroll
            for (int j = 0; j < 4; j++) d[r][j] = 0.f;
#pragma unroll 4
        for (int c = 0; c < 256; c++) {
            float ev[4];
#pragma unroll
            for (int j = 0; j < 4; j++) ev[j] = eT[(size_t)c * 1024 + t + 256 * j];
#pragma unroll
            for (int r = 0; r < 8; r++) {
                const float xv = xs[r][c];
                d[r][0] = fmaf(xv, ev[0], d[r][0]);
                d[r][1] = fmaf(xv, ev[1], d[r][1]);
                d[r][2] = fmaf(xv, ev[2], d[r][2]);
                d[r][3] = fmaf(xv, ev[3], d[r][3]);
            }
        }
#pragma unroll
        for (int r = 0; r < 8; r++) {
            unsigned long long best = ~0ull;
#pragma unroll
            for (int j = 0; j < 4; j++) {
                const float q = fmaf(-2.f, d[r][j], sx8[r]) + see[t + 256 * j];
                const unsigned long long pk =
                    ((unsigned long long)f32_sortable(q) << 32) | (unsigned int)(t + 256 * j);
                best = pk < best ? pk : best;
            }
            atomicMin(&key[nrow[r]], best);
        }
    }
}

// ---------------- k3: gather quantized + indices + loss finalize ----------------
__global__ __launch_bounds__(256) void k3_out(const float* __restrict__ emb,
                                              const unsigned long long* __restrict__ key,
                                              const double* __restrict__ loss,
                                              float* __restrict__ dout) {
    __shared__ float elds[32][257];
    __shared__ int   idxs[32];
    const int t  = threadIdx.x;
    const int bh = blockIdx.x;
    const int b = bh >> 5, h = bh & 31;
    if (t < 32) idxs[t] = (int)(key[(bh << 5) + t] & 0xffffffffull);
    __syncthreads();
    for (int r = 0; r < 32; r++) elds[r][t] = emb[(size_t)idxs[r] * 256 + t];
    __syncthreads();
    const int w = t & 31, cg = t >> 5;
    const size_t base = (size_t)b * 262144 + (size_t)(h * 32 + w);
#pragma unroll 4
    for (int s = 0; s < 32; s++) {
        const int c = (cg << 5) + s;
        dout[base + (size_t)c * 1024] = elds[w][c];
    }
    if (t < 32) dout[IDX_OFF + (bh << 5) + t] = (float)idxs[t];
    if (bh == 0 && t == 0)
        dout[LOSS_OFF] = (float)(1.25 * (*loss) / 8388608.0);
}

extern "C" void kernel_launch(void* const* d_in, const int* in_sizes, int n_in,
                              void* d_out, int out_size, void* d_ws, size_t ws_size,
                              hipStream_t stream) {
    const float* x   = (const float*)d_in[0];
    const float* emb = (const float*)d_in[1];
    float* dout = (float*)d_out;
    char* ws = (char*)d_ws;
    float*  see  = (float*)(ws + WS_SEE);
    float*  sxx  = (float*)(ws + WS_SXX);
    unsigned long long* key = (unsigned long long*)(ws + WS_KEY);
    int*    cnt  = (int*)(ws + WS_CNT);
    double* loss = (double*)(ws + WS_LOSS);
    int*    wl   = (int*)(ws + WS_WL);
    unsigned short* ebP = (unsigned short*)(ws + WS_EP);
    // eT (exact f32 transpose for k2r) lives in d_out's quantized region:
    // written by k_prep, read by k2r, overwritten by k3.
    float* eT = dout;

    k_prep <<<324,  256, 0, stream>>>(emb, ebP, see, eT, cnt, loss);
    k1_mfma<<<512,  512, 0, stream>>>(x, ebP, see, sxx, key, loss, cnt, wl);
    k2r    <<<128,  256, 0, stream>>>(x, eT, see, sxx, key, cnt, wl);
    k3_out <<<1024, 256, 0, stream>>>(emb, key, loss, dout);
}